// Round 4
// baseline (2686.955 us; speedup 1.0000x reference)
//
#include <hip/hip_runtime.h>
#include <hip/hip_bf16.h>
#include <float.h>

#define NN 3072
#define MM 3072
#define DD 64
#define KK 8
#define NPROB 24
#define NBPP 8            // blocks per problem in the sinkhorn kernel (per-problem barrier)

constexpr float C_EPS   = 0.0025f;   // blur^2
constexpr float C_SCAL2 = 0.64f;     // scaling^2
constexpr int   C_NITER = 30;
constexpr float LOG2E = 1.4426950408889634f;
constexpr float LN2F  = 0.6931471805599453f;
constexpr float L2_SCAL2 = -0.6438561897747247f;   // log2(0.64)

__device__ __forceinline__ float ex2(float x){ return __builtin_amdgcn_exp2f(x); }
__device__ __forceinline__ float lg2(float x){ return __builtin_amdgcn_logf(x); }

// workspace layout in 4-byte units
#define U_FILL 0        // 8 floats  (zeroed by memset)
#define U_MAXC 8        // 4 uints   (zeroed)
#define U_CNTX 12       // 8 int     (zeroed)
#define U_CNTY 20       // 8 int     (zeroed)
#define U_POSX 28       // 8 int     (zeroed)
#define U_POSY 36       // 8 int     (zeroed)
#define U_BCNT 44       // 24 int barrier counters (zeroed)
#define U_BGEN 68       // 24 int barrier generations (zeroed)  -> memset covers [0,92)
#define U_OFFX 92       // 9 int
#define U_OFFY 101      // 9 int
#define U_PNX  112      // 24 int
#define U_PNY  136
#define U_PRB  160
#define U_PCB  184
#define U_PRS  208
#define U_PCS  232
#define U_PCOFF 256     // 25 int
#define U_TOFF  281     // 25 int
#define U_ACCF  306     // 24 float (zeroed in k_offsets)
#define U_ACCG  330     // 24 float
#define U_XSQ  384      // 3072 float
#define U_YSQ  3456     // 3072 float
#define U_PRED 6528     // 3072 int
#define U_ROWS 9600     // 3072 int
#define U_COLS 12672    // 3072 int
#define U_FPOT 15744    // 24*3072 float potentials f
#define U_GPOT 89472    // 24*3072 float potentials g (zeroed by memset)
#define U_SUBC 163200   // compact submatrices (floats)

// ---------------- kernel 1: per-x-point: norms, argmin, softmax filling ----------------
__global__ __launch_bounds__(256) void k_prep_x(const float* __restrict__ x,
                                                const float* __restrict__ cc,
                                                float* wf, int* wi) {
    __shared__ __align__(16) float c_s[KK][DD];
    __shared__ float csq_s[KK];
    __shared__ float fpart[KK];
    int tid = threadIdx.x;
    for (int e = tid; e < KK*DD; e += 256) c_s[e>>6][e&63] = cc[e];
    if (tid < KK) fpart[tid] = 0.f;
    __syncthreads();
    if (tid < KK) { float s=0.f; for (int d=0; d<DD; ++d){ float v=c_s[tid][d]; s+=v*v; } csq_s[tid]=s; }
    __syncthreads();
    int i = blockIdx.x*256 + tid;
    if (i < NN) {
        const float4* xr = (const float4*)(x + (size_t)i*DD);
        float4 xv[16];
        float xs = 0.f;
        #pragma unroll
        for (int q=0;q<16;++q){ xv[q]=xr[q];
            xs += xv[q].x*xv[q].x + xv[q].y*xv[q].y + xv[q].z*xv[q].z + xv[q].w*xv[q].w; }
        float dk[KK];
        #pragma unroll
        for (int k=0;k<KK;++k){
            const float4* cr = (const float4*)(&c_s[k][0]);
            float dot=0.f;
            #pragma unroll
            for (int q=0;q<16;++q){ float4 cv=cr[q];
                dot += xv[q].x*cv.x + xv[q].y*cv.y + xv[q].z*cv.z + xv[q].w*cv.w; }
            dk[k] = xs + csq_s[k] - 2.f*dot;
        }
        float dmin = dk[0]; int am=0;
        #pragma unroll
        for (int k=1;k<KK;++k){ if (dk[k] < dmin){ dmin=dk[k]; am=k; } }
        float se=0.f; float ek[KK];
        #pragma unroll
        for (int k=0;k<KK;++k){ ek[k] = ex2((dmin-dk[k])*LOG2E); se+=ek[k]; }
        float inv = 1.f/se;
        #pragma unroll
        for (int k=0;k<KK;++k) atomicAdd(&fpart[k], ek[k]*inv);
        wf[U_XSQ + i] = xs;
        wi[U_PRED + i] = am;
        atomicAdd(&wi[U_CNTX + am], 1);
    }
    __syncthreads();
    if (tid < KK) atomicAdd(&wf[U_FILL + tid], fpart[tid]);
}

// ---------------- kernel 2: per-target: norms + counts ----------------
__global__ __launch_bounds__(256) void k_prep_y(const float* __restrict__ y,
                                                const int* __restrict__ predt,
                                                float* wf, int* wi) {
    int j = blockIdx.x*256 + threadIdx.x;
    if (j < MM) {
        const float4* yr = (const float4*)(y + (size_t)j*DD);
        float s=0.f;
        #pragma unroll
        for (int q=0;q<16;++q){ float4 v=yr[q]; s += v.x*v.x+v.y*v.y+v.z*v.z+v.w*v.w; }
        wf[U_YSQ + j] = s;
        atomicAdd(&wi[U_CNTY + predt[j]], 1);
    }
}

// ---------------- kernel 3: prefix sums, problem tables, loss_fil ----------------
__global__ void k_offsets(const float* __restrict__ ftarg, float* wf, int* wi, float* out) {
    if (threadIdx.x != 0) return;
    int offx=0, offy=0;
    wi[U_OFFX]=0; wi[U_OFFY]=0;
    for (int k=0;k<KK;++k){
        offx += wi[U_CNTX+k]; wi[U_OFFX+k+1]=offx;
        offy += wi[U_CNTY+k]; wi[U_OFFY+k+1]=offy;
    }
    int co=0, to=0;
    for (int k=0;k<KK;++k){
        int cx=wi[U_CNTX+k], cy=wi[U_CNTY+k];
        bool val = (cx>0)&&(cy>0);
        for (int t=0;t<3;++t){
            int p=k*3+t;
            int nx = val ? (t==2?cy:cx) : 0;
            int ny = val ? (t==1?cx:cy) : 0;
            wi[U_PNX+p]=nx; wi[U_PNY+p]=ny;
            wi[U_PRB+p] = (t==2)? wi[U_OFFY+k] : wi[U_OFFX+k];
            wi[U_PCB+p] = (t==1)? wi[U_OFFX+k] : wi[U_OFFY+k];
            wi[U_PRS+p] = (t==2)?1:0;
            wi[U_PCS+p] = (t==1)?0:1;
            wi[U_PCOFF+p]=co; co += nx*ny;
            wi[U_TOFF+p]=to; to += ((nx+31)>>5)*((ny+31)>>5);
            wf[U_ACCF+p]=0.f; wf[U_ACCG+p]=0.f;
        }
    }
    wi[U_PCOFF+NPROB]=co; wi[U_TOFF+NPROB]=to;
    float lf=0.f;
    for (int k=0;k<KK;++k){ float fx = wf[U_FILL+k]/(float)NN; float dd = fx - ftarg[k]; lf += dd*dd; }
    out[0] = lf/(float)KK;
}

// ---------------- kernel 4: scatter compact index lists ----------------
__global__ __launch_bounds__(256) void k_scatter(const int* __restrict__ predt, int* wi) {
    int b = blockIdx.x;
    if (b < 12) {
        int i = b*256 + threadIdx.x;
        if (i < NN){ int k = wi[U_PRED+i]; int p = atomicAdd(&wi[U_POSX+k],1);
                     wi[U_ROWS + wi[U_OFFX+k] + p] = i; }
    } else {
        int j = (b-12)*256 + threadIdx.x;
        if (j < MM){ int k = predt[j]; int p = atomicAdd(&wi[U_POSY+k],1);
                     wi[U_COLS + wi[U_OFFY+k] + p] = j; }
    }
}

// ---------------- kernel 5: exact max over full cost matrices (tiled) ----------------
__global__ __launch_bounds__(256) void k_maxmat(const float* __restrict__ x,
                                                const float* __restrict__ y,
                                                float* wf, int* wi) {
    int z = blockIdx.z;
    const float* A = (z==2)? y : x;
    const float* B = (z==0)? y : ((z==1)? x : y);
    int aqo = (z==2)? U_YSQ : U_XSQ;
    int bqo = (z==1)? U_XSQ : U_YSQ;
    __shared__ float la[64][65];
    __shared__ float lb[64][65];
    __shared__ float laq[64], lbq[64];
    __shared__ float wred[4];
    int tid = threadIdx.x;
    int i0 = blockIdx.y*64, j0 = blockIdx.x*64;
    #pragma unroll
    for (int q=0;q<4;++q){
        int idx4 = tid + q*256;
        int r = idx4>>4; int c = (idx4&15)<<2;
        float4 va = *(const float4*)(A + (size_t)(i0+r)*DD + c);
        la[r][c]=va.x; la[r][c+1]=va.y; la[r][c+2]=va.z; la[r][c+3]=va.w;
        float4 vb = *(const float4*)(B + (size_t)(j0+r)*DD + c);
        lb[r][c]=vb.x; lb[r][c+1]=vb.y; lb[r][c+2]=vb.z; lb[r][c+3]=vb.w;
    }
    if (tid < 64) { laq[tid]=wf[aqo+i0+tid]; lbq[tid]=wf[bqo+j0+tid]; }
    __syncthreads();
    int r0 = (tid>>4)<<2, c0 = (tid&15)<<2;
    float acc[4][4] = {};
    for (int d=0; d<DD; ++d){
        float av[4], bv[4];
        #pragma unroll
        for (int a=0;a<4;++a){ av[a]=la[r0+a][d]; bv[a]=lb[c0+a][d]; }
        #pragma unroll
        for (int a=0;a<4;++a)
            #pragma unroll
            for (int b2=0;b2<4;++b2) acc[a][b2] += av[a]*bv[b2];
    }
    float m = 0.f;
    #pragma unroll
    for (int a=0;a<4;++a)
        #pragma unroll
        for (int b2=0;b2<4;++b2){
            float cst = 0.5f*(laq[r0+a]+lbq[c0+b2]) - acc[a][b2];
            m = fmaxf(m, cst);
        }
    #pragma unroll
    for (int o=32;o;o>>=1) m = fmaxf(m, __shfl_xor(m,o));
    int wid = tid>>6;
    if ((tid&63)==0) wred[wid]=m;
    __syncthreads();
    if (tid==0){
        float mm = fmaxf(fmaxf(wred[0],wred[1]),fmaxf(wred[2],wred[3]));
        atomicMax((unsigned int*)&wi[U_MAXC+z], __float_as_uint(mm));
    }
}

// ---------------- kernel 6: gather compact per-problem cost submatrices ----------------
__global__ __launch_bounds__(256) void k_gather(const float* __restrict__ x,
                                                const float* __restrict__ y,
                                                float* wf, int* wi) {
    __shared__ float xs_[32][65], ys_[32][65];
    __shared__ float rq[32], cq[32];
    __shared__ int toff_s[NPROB+1];
    int tid = threadIdx.x;
    if (tid <= NPROB) toff_s[tid] = wi[U_TOFF+tid];
    __syncthreads();
    int total = toff_s[NPROB];
    for (int tix = blockIdx.x; tix < total; tix += gridDim.x){
        int p = 0;
        while (toff_s[p+1] <= tix) ++p;
        int nx = wi[U_PNX+p], ny = wi[U_PNY+p];
        int tpr = (ny+31)>>5;
        int loc = tix - toff_s[p];
        int i0 = (loc/tpr)<<5, j0 = (loc%tpr)<<5;
        int rbase = wi[U_PRB+p], cbase = wi[U_PCB+p];
        int rs = wi[U_PRS+p], cs = wi[U_PCS+p];
        const float* rsrc = rs? y : x;
        const float* csrc = cs? y : x;
        const int* rlist = wi + (rs? U_COLS : U_ROWS);
        const int* clist = wi + (cs? U_COLS : U_ROWS);
        int rqo = rs? U_YSQ : U_XSQ;
        int cqo = cs? U_YSQ : U_XSQ;
        size_t coff = (size_t)wi[U_PCOFF+p];
        #pragma unroll
        for (int q=0;q<2;++q){
            int idx4 = tid + q*256;      // 0..511
            int r = idx4>>4, c = (idx4&15)<<2;
            if (i0 + r < nx){
                int gi = rlist[rbase + i0 + r];
                float4 v = *(const float4*)(rsrc + (size_t)gi*DD + c);
                xs_[r][c]=v.x; xs_[r][c+1]=v.y; xs_[r][c+2]=v.z; xs_[r][c+3]=v.w;
                if (c==0) rq[r] = wf[rqo + gi];
            }
            if (j0 + r < ny){
                int gj = clist[cbase + j0 + r];
                float4 v = *(const float4*)(csrc + (size_t)gj*DD + c);
                ys_[r][c]=v.x; ys_[r][c+1]=v.y; ys_[r][c+2]=v.z; ys_[r][c+3]=v.w;
                if (c==0) cq[r] = wf[cqo + gj];
            }
        }
        __syncthreads();
        int r = tid>>3, cb = (tid&7)<<2;
        if (i0 + r < nx){
            float acc[4] = {0.f,0.f,0.f,0.f};
            for (int d=0; d<DD; ++d){
                float xv = xs_[r][d];
                #pragma unroll
                for (int q=0;q<4;++q) acc[q] += xv*ys_[cb+q][d];
            }
            float* dst = wf + U_SUBC + coff + (size_t)(i0+r)*ny + j0;
            #pragma unroll
            for (int q=0;q<4;++q){
                int j = cb+q;
                if (j0 + j < ny) dst[j] = 0.5f*(rq[r]+cq[j]) - acc[q];
            }
        }
        __syncthreads();
    }
}

// ---------------- per-problem 8-block barrier (device-scope, sense via generation) ----------
// Safe without cooperative launch: grid (192 blocks x 16 waves = 3072 waves) is far below
// device capacity (8192 waves), so all participant blocks are resident before any waits.
__device__ __forceinline__ void pbar(int* cnt, int* gen){
    __syncthreads();
    if (threadIdx.x == 0){
        int g0 = __hip_atomic_load(gen, __ATOMIC_RELAXED, __HIP_MEMORY_SCOPE_AGENT);
        int a  = __hip_atomic_fetch_add(cnt, 1, __ATOMIC_ACQ_REL, __HIP_MEMORY_SCOPE_AGENT);
        if (a == NBPP-1){
            __hip_atomic_store(cnt, 0, __ATOMIC_RELAXED, __HIP_MEMORY_SCOPE_AGENT);
            __hip_atomic_fetch_add(gen, 1, __ATOMIC_ACQ_REL, __HIP_MEMORY_SCOPE_AGENT);
        } else {
            while (__hip_atomic_load(gen, __ATOMIC_ACQUIRE, __HIP_MEMORY_SCOPE_AGENT) == g0)
                __builtin_amdgcn_s_sleep(2);
        }
    }
    __syncthreads();
}

__device__ __forceinline__ void lsemerge(float& m, float& S, float mo, float So){
    float mn = fmaxf(m, mo);
    S = S*ex2(m-mn) + So*ex2(mo-mn);
    m = mn;
}

// ---------------- kernel 7: whole sinkhorn loop, one REGULAR launch ----------------
// grid = NPROB*NBPP blocks x 1024 threads; 8 blocks team up per OT problem.
__global__ __launch_bounds__(1024) void k_sink(float* wf, int* wi, float* out) {
    int b  = blockIdx.x;
    int p  = b >> 3;           // problem id
    int sb = b & 7;            // sub-block within problem
    int nx = wi[U_PNX+p], ny = wi[U_PNY+p];
    if (nx <= 0 || ny <= 0) return;          // uniform across the problem's 8 blocks
    int tid = threadIdx.x, w = tid>>6, lane = tid&63;
    int gwv = sb*16 + w;                     // 0..127: global wave id within problem
    float eps0 = fmaxf(__uint_as_float((unsigned)wi[U_MAXC + (p%3)]), C_EPS);
    const float* C = wf + U_SUBC + (size_t)wi[U_PCOFF+p];
    float* f = wf + U_FPOT + p*3072;
    float* g = wf + U_GPOT + p*3072;
    float l2ny = lg2((float)ny), l2nx = lg2((float)nx);
    int* bcnt = wi + U_BCNT + p;
    int* bgen = wi + U_BGEN + p;
    int c8 = lane&7, rs = lane>>3;

    for (int it=0; it<C_NITER; ++it){
        float eps = fmaxf(eps0*ex2((float)it*L2_SCAL2), C_EPS);
        float ie2 = LOG2E/eps, neL = -eps*LN2F;
        // ---- f-phase: wave per row, online LSE over columns ----
        for (int i=gwv; i<nx; i+=128){
            const float* Cr = C + (size_t)i*ny;
            float m=-FLT_MAX, S=0.f;
            for (int j=lane; j<ny; j+=64){
                float u = fmaf(Cr[j], -ie2, g[j]*ie2);
                float mn = fmaxf(m,u);
                S = S*ex2(m-mn) + ex2(u-mn);
                m = mn;
            }
            #pragma unroll
            for (int o=32;o;o>>=1) lsemerge(m,S,__shfl_xor(m,o),__shfl_xor(S,o));
            if (lane==0) f[i] = neL*(m + lg2(S) - l2ny);
        }
        pbar(bcnt, bgen);
        // ---- g-phase: wave = 8-col tile x 8-row-split ----
        int T = (ny+7)>>3;
        for (int t=gwv; t<T; t+=128){
            int j = (t<<3) + c8;
            float m=-FLT_MAX, S=0.f;
            if (j < ny){
                const float* Cc = C + j;
                for (int i=rs; i<nx; i+=8){
                    float u = fmaf(Cc[(size_t)i*ny], -ie2, f[i]*ie2);
                    float mn = fmaxf(m,u);
                    S = S*ex2(m-mn) + ex2(u-mn);
                    m = mn;
                }
            }
            #pragma unroll
            for (int o=8;o<64;o<<=1) lsemerge(m,S,__shfl_xor(m,o),__shfl_xor(S,o));
            if (rs==0 && j<ny) g[j] = neL*(m + lg2(S) - l2nx);
        }
        pbar(bcnt, bgen);
    }
    // ---- final differentiable update at eps=EPS: f2 (no overwrite) and g2 (uses stored f) ----
    __shared__ float sacc[2];
    if (tid<2) sacc[tid]=0.f;
    __syncthreads();
    {
        float eps = C_EPS, ie2 = LOG2E/eps, neL = -eps*LN2F;
        float lf2 = 0.f;
        for (int i=gwv; i<nx; i+=128){
            const float* Cr = C + (size_t)i*ny;
            float m=-FLT_MAX, S=0.f;
            for (int j=lane; j<ny; j+=64){
                float u = fmaf(Cr[j], -ie2, g[j]*ie2);
                float mn = fmaxf(m,u);
                S = S*ex2(m-mn) + ex2(u-mn);
                m = mn;
            }
            #pragma unroll
            for (int o=32;o;o>>=1) lsemerge(m,S,__shfl_xor(m,o),__shfl_xor(S,o));
            if (lane==0) lf2 += neL*(m + lg2(S) - l2ny);
        }
        if (lane==0 && lf2!=0.f) atomicAdd(&sacc[0], lf2);
        float lg2a = 0.f;
        int T = (ny+7)>>3;
        for (int t=gwv; t<T; t+=128){
            int j = (t<<3) + c8;
            float m=-FLT_MAX, S=0.f;
            if (j < ny){
                const float* Cc = C + j;
                for (int i=rs; i<nx; i+=8){
                    float u = fmaf(Cc[(size_t)i*ny], -ie2, f[i]*ie2);
                    float mn = fmaxf(m,u);
                    S = S*ex2(m-mn) + ex2(u-mn);
                    m = mn;
                }
            }
            #pragma unroll
            for (int o=8;o<64;o<<=1) lsemerge(m,S,__shfl_xor(m,o),__shfl_xor(S,o));
            if (rs==0 && j<ny) lg2a += neL*(m + lg2(S) - l2nx);
        }
        if (rs==0 && lg2a!=0.f) atomicAdd(&sacc[1], lg2a);
    }
    __syncthreads();
    if (tid==0){
        if (sacc[0]!=0.f) atomicAdd(&wf[U_ACCF+p], sacc[0]);
        if (sacc[1]!=0.f) atomicAdd(&wf[U_ACCG+p], sacc[1]);
    }
    pbar(bcnt, bgen);
    if (sb==0 && tid==0){
        float af = __hip_atomic_load(&wf[U_ACCF+p], __ATOMIC_ACQUIRE, __HIP_MEMORY_SCOPE_AGENT);
        float ag = __hip_atomic_load(&wf[U_ACCG+p], __ATOMIC_ACQUIRE, __HIP_MEMORY_SCOPE_AGENT);
        float wgt = (p%3==0) ? 1.f : -0.5f;
        atomicAdd(out, wgt*(af/(float)nx + ag/(float)ny));
    }
}

extern "C" void kernel_launch(void* const* d_in, const int* in_sizes, int n_in,
                              void* d_out, int out_size, void* d_ws, size_t ws_size,
                              hipStream_t stream) {
    const float* x     = (const float*)d_in[0];
    const float* y     = (const float*)d_in[1];
    const float* cc    = (const float*)d_in[2];
    const float* ft    = (const float*)d_in[3];
    const int*   predt = (const int*)d_in[4];
    float* out = (float*)d_out;
    float* wf = (float*)d_ws;
    int*   wi = (int*)d_ws;

    hipMemsetAsync(d_ws, 0, 92*sizeof(int), stream);                      // counters/maxes/barriers
    hipMemsetAsync(wf + U_GPOT, 0, NPROB*3072*sizeof(float), stream);     // g potentials start at 0

    k_prep_x<<<12, 256, 0, stream>>>(x, cc, wf, wi);
    k_prep_y<<<12, 256, 0, stream>>>(y, predt, wf, wi);
    k_offsets<<<1, 64, 0, stream>>>(ft, wf, wi, out);   // writes out[0] = loss_fil, tables, zero accs
    k_scatter<<<24, 256, 0, stream>>>(predt, wi);
    k_maxmat<<<dim3(48,48,3), 256, 0, stream>>>(x, y, wf, wi);
    k_gather<<<1024, 256, 0, stream>>>(x, y, wf, wi);

    k_sink<<<dim3(NPROB*NBPP), 1024, 0, stream>>>(wf, wi, out);   // regular launch (graph-capturable)
}

// Round 5
// 2428.054 us; speedup vs baseline: 1.1066x; 1.1066x over previous
//
#include <hip/hip_runtime.h>
#include <hip/hip_bf16.h>
#include <float.h>

#define NN 3072
#define MM 3072
#define DD 64
#define KK 8
#define NPROB 24
#define NBPP 8            // blocks per problem (per-problem barrier team)

constexpr float C_EPS   = 0.0025f;   // blur^2
constexpr int   C_NITER = 30;
constexpr float LOG2E = 1.4426950408889634f;
constexpr float LN2F  = 0.6931471805599453f;
constexpr float L2_SCAL2 = -0.6438561897747247f;   // log2(0.64)

__device__ __forceinline__ float ex2(float x){ return __builtin_amdgcn_exp2f(x); }
__device__ __forceinline__ float lg2(float x){ return __builtin_amdgcn_logf(x); }

// workspace layout in 4-byte units
#define U_FILL 0        // 8 floats  (zeroed by memset)
#define U_MAXC 8        // 4 uints   (zeroed)
#define U_CNTX 12       // 8 int
#define U_CNTY 20       // 8 int
#define U_POSX 28       // 8 int
#define U_POSY 36       // 8 int
#define U_BAR  64       // 24 problems x 32 ints: cnt at +p*32, gen at +p*32+16 (zeroed)
                        // memset covers [0, 832)
#define U_OFFX 832      // 9 int
#define U_OFFY 841      // 9 int
#define U_PNX  864      // 24 int
#define U_PNY  888
#define U_PRB  912
#define U_PCB  936
#define U_PRS  960
#define U_PCS  984
#define U_PCOFF 1008    // 25 int
#define U_PTOF  1033    // 24 int  (C^T offsets; == PCOFF for symmetric xx/yy)
#define U_TOFF  1057    // 25 int
#define U_ACCF  1088    // 24 float (zeroed in k_offsets)
#define U_ACCG  1112    // 24 float
#define U_XSQ  1152     // 3072 float
#define U_YSQ  4224     // 3072 float
#define U_PRED 7296     // 3072 int
#define U_ROWS 10368    // 3072 int
#define U_COLS 13440    // 3072 int
#define U_FPOT 16512    // 24*3072 float potentials f
#define U_GPOT 90240    // 24*3072 float potentials g (zeroed by memset)
#define U_SUBC 164096   // compact submatrices C, then appended C^T blocks (floats)

// ---------------- kernel 1: per-x-point: norms, argmin, softmax filling ----------------
__global__ __launch_bounds__(256) void k_prep_x(const float* __restrict__ x,
                                                const float* __restrict__ cc,
                                                float* wf, int* wi) {
    __shared__ __align__(16) float c_s[KK][DD];
    __shared__ float csq_s[KK];
    __shared__ float fpart[KK];
    int tid = threadIdx.x;
    for (int e = tid; e < KK*DD; e += 256) c_s[e>>6][e&63] = cc[e];
    if (tid < KK) fpart[tid] = 0.f;
    __syncthreads();
    if (tid < KK) { float s=0.f; for (int d=0; d<DD; ++d){ float v=c_s[tid][d]; s+=v*v; } csq_s[tid]=s; }
    __syncthreads();
    int i = blockIdx.x*256 + tid;
    if (i < NN) {
        const float4* xr = (const float4*)(x + (size_t)i*DD);
        float4 xv[16];
        float xs = 0.f;
        #pragma unroll
        for (int q=0;q<16;++q){ xv[q]=xr[q];
            xs += xv[q].x*xv[q].x + xv[q].y*xv[q].y + xv[q].z*xv[q].z + xv[q].w*xv[q].w; }
        float dk[KK];
        #pragma unroll
        for (int k=0;k<KK;++k){
            const float4* cr = (const float4*)(&c_s[k][0]);
            float dot=0.f;
            #pragma unroll
            for (int q=0;q<16;++q){ float4 cv=cr[q];
                dot += xv[q].x*cv.x + xv[q].y*cv.y + xv[q].z*cv.z + xv[q].w*cv.w; }
            dk[k] = xs + csq_s[k] - 2.f*dot;
        }
        float dmin = dk[0]; int am=0;
        #pragma unroll
        for (int k=1;k<KK;++k){ if (dk[k] < dmin){ dmin=dk[k]; am=k; } }
        float se=0.f; float ek[KK];
        #pragma unroll
        for (int k=0;k<KK;++k){ ek[k] = ex2((dmin-dk[k])*LOG2E); se+=ek[k]; }
        float inv = 1.f/se;
        #pragma unroll
        for (int k=0;k<KK;++k) atomicAdd(&fpart[k], ek[k]*inv);
        wf[U_XSQ + i] = xs;
        wi[U_PRED + i] = am;
        atomicAdd(&wi[U_CNTX + am], 1);
    }
    __syncthreads();
    if (tid < KK) atomicAdd(&wf[U_FILL + tid], fpart[tid]);
}

// ---------------- kernel 2: per-target: norms + counts ----------------
__global__ __launch_bounds__(256) void k_prep_y(const float* __restrict__ y,
                                                const int* __restrict__ predt,
                                                float* wf, int* wi) {
    int j = blockIdx.x*256 + threadIdx.x;
    if (j < MM) {
        const float4* yr = (const float4*)(y + (size_t)j*DD);
        float s=0.f;
        #pragma unroll
        for (int q=0;q<16;++q){ float4 v=yr[q]; s += v.x*v.x+v.y*v.y+v.z*v.z+v.w*v.w; }
        wf[U_YSQ + j] = s;
        atomicAdd(&wi[U_CNTY + predt[j]], 1);
    }
}

// ---------------- kernel 3: prefix sums, problem tables, loss_fil ----------------
__global__ void k_offsets(const float* __restrict__ ftarg, float* wf, int* wi, float* out) {
    if (threadIdx.x != 0) return;
    int offx=0, offy=0;
    wi[U_OFFX]=0; wi[U_OFFY]=0;
    for (int k=0;k<KK;++k){
        offx += wi[U_CNTX+k]; wi[U_OFFX+k+1]=offx;
        offy += wi[U_CNTY+k]; wi[U_OFFY+k+1]=offy;
    }
    int co=0, to=0;
    for (int k=0;k<KK;++k){
        int cx=wi[U_CNTX+k], cy=wi[U_CNTY+k];
        bool val = (cx>0)&&(cy>0);
        for (int t=0;t<3;++t){
            int p=k*3+t;
            int nx = val ? (t==2?cy:cx) : 0;
            int ny = val ? (t==1?cx:cy) : 0;
            wi[U_PNX+p]=nx; wi[U_PNY+p]=ny;
            wi[U_PRB+p] = (t==2)? wi[U_OFFY+k] : wi[U_OFFX+k];
            wi[U_PCB+p] = (t==1)? wi[U_OFFX+k] : wi[U_OFFY+k];
            wi[U_PRS+p] = (t==2)?1:0;
            wi[U_PCS+p] = (t==1)?0:1;
            wi[U_PCOFF+p]=co; co += nx*ny;
            wi[U_TOFF+p]=to; to += ((nx+31)>>5)*((ny+31)>>5);
            wf[U_ACCF+p]=0.f; wf[U_ACCG+p]=0.f;
        }
    }
    wi[U_PCOFF+NPROB]=co; wi[U_TOFF+NPROB]=to;
    // C^T blocks appended after all C; xx/yy are symmetric so CT == C
    int cto = co;
    for (int p=0;p<NPROB;++p){
        if (p%3 == 0){ wi[U_PTOF+p] = cto; cto += wi[U_PNX+p]*wi[U_PNY+p]; }
        else         { wi[U_PTOF+p] = wi[U_PCOFF+p]; }
    }
    float lf=0.f;
    for (int k=0;k<KK;++k){ float fx = wf[U_FILL+k]/(float)NN; float dd = fx - ftarg[k]; lf += dd*dd; }
    out[0] = lf/(float)KK;
}

// ---------------- kernel 4: scatter compact index lists ----------------
__global__ __launch_bounds__(256) void k_scatter(const int* __restrict__ predt, int* wi) {
    int b = blockIdx.x;
    if (b < 12) {
        int i = b*256 + threadIdx.x;
        if (i < NN){ int k = wi[U_PRED+i]; int p = atomicAdd(&wi[U_POSX+k],1);
                     wi[U_ROWS + wi[U_OFFX+k] + p] = i; }
    } else {
        int j = (b-12)*256 + threadIdx.x;
        if (j < MM){ int k = predt[j]; int p = atomicAdd(&wi[U_POSY+k],1);
                     wi[U_COLS + wi[U_OFFY+k] + p] = j; }
    }
}

// ---------------- kernel 5: exact max over full cost matrices (tiled) ----------------
__global__ __launch_bounds__(256) void k_maxmat(const float* __restrict__ x,
                                                const float* __restrict__ y,
                                                float* wf, int* wi) {
    int z = blockIdx.z;
    const float* A = (z==2)? y : x;
    const float* B = (z==0)? y : ((z==1)? x : y);
    int aqo = (z==2)? U_YSQ : U_XSQ;
    int bqo = (z==1)? U_XSQ : U_YSQ;
    __shared__ float la[64][65];
    __shared__ float lb[64][65];
    __shared__ float laq[64], lbq[64];
    __shared__ float wred[4];
    int tid = threadIdx.x;
    int i0 = blockIdx.y*64, j0 = blockIdx.x*64;
    #pragma unroll
    for (int q=0;q<4;++q){
        int idx4 = tid + q*256;
        int r = idx4>>4; int c = (idx4&15)<<2;
        float4 va = *(const float4*)(A + (size_t)(i0+r)*DD + c);
        la[r][c]=va.x; la[r][c+1]=va.y; la[r][c+2]=va.z; la[r][c+3]=va.w;
        float4 vb = *(const float4*)(B + (size_t)(j0+r)*DD + c);
        lb[r][c]=vb.x; lb[r][c+1]=vb.y; lb[r][c+2]=vb.z; lb[r][c+3]=vb.w;
    }
    if (tid < 64) { laq[tid]=wf[aqo+i0+tid]; lbq[tid]=wf[bqo+j0+tid]; }
    __syncthreads();
    int r0 = (tid>>4)<<2, c0 = (tid&15)<<2;
    float acc[4][4] = {};
    for (int d=0; d<DD; ++d){
        float av[4], bv[4];
        #pragma unroll
        for (int a=0;a<4;++a){ av[a]=la[r0+a][d]; bv[a]=lb[c0+a][d]; }
        #pragma unroll
        for (int a=0;a<4;++a)
            #pragma unroll
            for (int b2=0;b2<4;++b2) acc[a][b2] += av[a]*bv[b2];
    }
    float m = 0.f;
    #pragma unroll
    for (int a=0;a<4;++a)
        #pragma unroll
        for (int b2=0;b2<4;++b2){
            float cst = 0.5f*(laq[r0+a]+lbq[c0+b2]) - acc[a][b2];
            m = fmaxf(m, cst);
        }
    #pragma unroll
    for (int o=32;o;o>>=1) m = fmaxf(m, __shfl_xor(m,o));
    int wid = tid>>6;
    if ((tid&63)==0) wred[wid]=m;
    __syncthreads();
    if (tid==0){
        float mm = fmaxf(fmaxf(wred[0],wred[1]),fmaxf(wred[2],wred[3]));
        atomicMax((unsigned int*)&wi[U_MAXC+z], __float_as_uint(mm));
    }
}

// ---------------- kernel 6: gather compact cost submatrices (+ C^T for xy) ----------------
__global__ __launch_bounds__(256) void k_gather(const float* __restrict__ x,
                                                const float* __restrict__ y,
                                                float* wf, int* wi) {
    __shared__ float xs_[32][65], ys_[32][65];
    __shared__ float cs_[32][33];
    __shared__ float rq[32], cq[32];
    __shared__ int toff_s[NPROB+1];
    int tid = threadIdx.x;
    if (tid <= NPROB) toff_s[tid] = wi[U_TOFF+tid];
    __syncthreads();
    int total = toff_s[NPROB];
    for (int tix = blockIdx.x; tix < total; tix += gridDim.x){
        int p = 0;
        while (toff_s[p+1] <= tix) ++p;
        int nx = wi[U_PNX+p], ny = wi[U_PNY+p];
        int tpr = (ny+31)>>5;
        int loc = tix - toff_s[p];
        int i0 = (loc/tpr)<<5, j0 = (loc%tpr)<<5;
        int rbase = wi[U_PRB+p], cbase = wi[U_PCB+p];
        int rs = wi[U_PRS+p], cs = wi[U_PCS+p];
        const float* rsrc = rs? y : x;
        const float* csrc = cs? y : x;
        const int* rlist = wi + (rs? U_COLS : U_ROWS);
        const int* clist = wi + (cs? U_COLS : U_ROWS);
        int rqo = rs? U_YSQ : U_XSQ;
        int cqo = cs? U_YSQ : U_XSQ;
        size_t coff = (size_t)wi[U_PCOFF+p];
        #pragma unroll
        for (int q=0;q<2;++q){
            int idx4 = tid + q*256;      // 0..511
            int r = idx4>>4, c = (idx4&15)<<2;
            if (i0 + r < nx){
                int gi = rlist[rbase + i0 + r];
                float4 v = *(const float4*)(rsrc + (size_t)gi*DD + c);
                xs_[r][c]=v.x; xs_[r][c+1]=v.y; xs_[r][c+2]=v.z; xs_[r][c+3]=v.w;
                if (c==0) rq[r] = wf[rqo + gi];
            }
            if (j0 + r < ny){
                int gj = clist[cbase + j0 + r];
                float4 v = *(const float4*)(csrc + (size_t)gj*DD + c);
                ys_[r][c]=v.x; ys_[r][c+1]=v.y; ys_[r][c+2]=v.z; ys_[r][c+3]=v.w;
                if (c==0) cq[r] = wf[cqo + gj];
            }
        }
        __syncthreads();
        int r = tid>>3, cb = (tid&7)<<2;
        float cv[4] = {0.f,0.f,0.f,0.f};
        if (i0 + r < nx){
            float acc[4] = {0.f,0.f,0.f,0.f};
            for (int d=0; d<DD; ++d){
                float xv = xs_[r][d];
                #pragma unroll
                for (int q=0;q<4;++q) acc[q] += xv*ys_[cb+q][d];
            }
            float* dst = wf + U_SUBC + coff + (size_t)(i0+r)*ny + j0;
            #pragma unroll
            for (int q=0;q<4;++q){
                int j = cb+q;
                cv[q] = 0.5f*(rq[r]+cq[j]) - acc[q];
                if (j0 + j < ny) dst[j] = cv[q];
            }
        }
        if (p%3 == 0){
            // stash tile, write transposed (coalesced along nx) into CT
            #pragma unroll
            for (int q=0;q<4;++q) cs_[r][cb+q] = cv[q];
            __syncthreads();
            if (j0 + r < ny){
                float* dT = wf + U_SUBC + (size_t)wi[U_PTOF+p] + (size_t)(j0+r)*nx + i0;
                #pragma unroll
                for (int q=0;q<4;++q){
                    int ii = cb+q;
                    if (i0 + ii < nx) dT[ii] = cs_[ii][r];
                }
            }
        }
        __syncthreads();
    }
}

// ---------------- per-problem 8-block barrier (padded line, XCD-local team) ----------
__device__ __forceinline__ void pbar(int* cnt, int* gen){
    __syncthreads();
    if (threadIdx.x == 0){
        int g0 = __hip_atomic_load(gen, __ATOMIC_RELAXED, __HIP_MEMORY_SCOPE_AGENT);
        int a  = __hip_atomic_fetch_add(cnt, 1, __ATOMIC_ACQ_REL, __HIP_MEMORY_SCOPE_AGENT);
        if (a == NBPP-1){
            __hip_atomic_store(cnt, 0, __ATOMIC_RELAXED, __HIP_MEMORY_SCOPE_AGENT);
            __hip_atomic_fetch_add(gen, 1, __ATOMIC_ACQ_REL, __HIP_MEMORY_SCOPE_AGENT);
        } else {
            while (__hip_atomic_load(gen, __ATOMIC_ACQUIRE, __HIP_MEMORY_SCOPE_AGENT) == g0)
                __builtin_amdgcn_s_sleep(4);
        }
    }
    __syncthreads();
}

__device__ __forceinline__ void lsemerge(float& m, float& S, float mo, float So){
    float mn = fmaxf(m, mo);
    S = S*ex2(m-mn) + So*ex2(mo-mn);
    m = mn;
}

// ---------------- kernel 7: whole sinkhorn loop, one regular launch ----------------
// grid = 192 blocks x 1024 threads. Team mapping puts a problem's 8 blocks on ONE XCD
// (heuristic: consecutive blockIdx round-robin across the 8 XCDs; perf-only, not correctness).
__global__ __launch_bounds__(1024) void k_sink(float* wf, int* wi, float* out) {
    int b  = blockIdx.x;
    int p  = (b&7)*3 + ((b>>3)%3);   // problem id (3 problems per XCD)
    int sb = (b>>3)/3;               // 0..7 sub-block within problem
    int nx = wi[U_PNX+p], ny = wi[U_PNY+p];
    if (nx <= 0 || ny <= 0) return;  // uniform across the problem's 8 blocks
    int tid = threadIdx.x, w = tid>>6, lane = tid&63;
    int gwv = sb*16 + w;             // 0..127: global wave id within problem
    float eps0 = fmaxf(__uint_as_float((unsigned)wi[U_MAXC + (p%3)]), C_EPS);
    const float* C  = wf + U_SUBC + (size_t)wi[U_PCOFF+p];
    const float* CT = wf + U_SUBC + (size_t)wi[U_PTOF+p];
    float* f = wf + U_FPOT + p*3072;
    float* g = wf + U_GPOT + p*3072;
    float l2ny = lg2((float)ny), l2nx = lg2((float)nx);
    int* bcnt = wi + U_BAR + p*32;
    int* bgen = bcnt + 16;
    __shared__ float pot[3072];
    __shared__ float sacc[2];
    if (tid < 2) sacc[tid] = 0.f;

    for (int it=0; it<C_NITER; ++it){
        float eps = fmaxf(eps0*ex2((float)it*L2_SCAL2), C_EPS);
        float ie2 = LOG2E/eps, neL = -eps*LN2F;
        // ---- f-phase: stage g*ie2 in LDS; wave per row of C (coalesced) ----
        for (int j=tid; j<ny; j+=1024) pot[j] = g[j]*ie2;
        __syncthreads();
        for (int i=gwv; i<nx; i+=128){
            const float* Cr = C + (size_t)i*ny;
            float m=-FLT_MAX, S=0.f;
            for (int j=lane; j<ny; j+=64){
                float u = fmaf(Cr[j], -ie2, pot[j]);
                float mn = fmaxf(m,u);
                S = S*ex2(m-mn) + ex2(u-mn);
                m = mn;
            }
            #pragma unroll
            for (int o=32;o;o>>=1) lsemerge(m,S,__shfl_xor(m,o),__shfl_xor(S,o));
            if (lane==0) f[i] = neL*(m + lg2(S) - l2ny);
        }
        pbar(bcnt, bgen);
        // ---- g-phase: stage f*ie2 in LDS; wave per row of CT (coalesced) ----
        for (int i=tid; i<nx; i+=1024) pot[i] = f[i]*ie2;
        __syncthreads();
        for (int j=gwv; j<ny; j+=128){
            const float* Tr = CT + (size_t)j*nx;
            float m=-FLT_MAX, S=0.f;
            for (int i=lane; i<nx; i+=64){
                float u = fmaf(Tr[i], -ie2, pot[i]);
                float mn = fmaxf(m,u);
                S = S*ex2(m-mn) + ex2(u-mn);
                m = mn;
            }
            #pragma unroll
            for (int o=32;o;o>>=1) lsemerge(m,S,__shfl_xor(m,o),__shfl_xor(S,o));
            if (lane==0) g[j] = neL*(m + lg2(S) - l2nx);
        }
        pbar(bcnt, bgen);
    }
    // ---- final differentiable update at eps=EPS: f2 (no overwrite), g2 (uses stored f) ----
    {
        float ie2 = LOG2E/C_EPS, neL = -C_EPS*LN2F;
        for (int j=tid; j<ny; j+=1024) pot[j] = g[j]*ie2;
        __syncthreads();
        float lf2 = 0.f;
        for (int i=gwv; i<nx; i+=128){
            const float* Cr = C + (size_t)i*ny;
            float m=-FLT_MAX, S=0.f;
            for (int j=lane; j<ny; j+=64){
                float u = fmaf(Cr[j], -ie2, pot[j]);
                float mn = fmaxf(m,u);
                S = S*ex2(m-mn) + ex2(u-mn);
                m = mn;
            }
            #pragma unroll
            for (int o=32;o;o>>=1) lsemerge(m,S,__shfl_xor(m,o),__shfl_xor(S,o));
            lf2 += neL*(m + lg2(S) - l2ny);
        }
        if (lane==0 && lf2!=0.f) atomicAdd(&sacc[0], lf2);
        __syncthreads();
        for (int i=tid; i<nx; i+=1024) pot[i] = f[i]*ie2;
        __syncthreads();
        float lg2a = 0.f;
        for (int j=gwv; j<ny; j+=128){
            const float* Tr = CT + (size_t)j*nx;
            float m=-FLT_MAX, S=0.f;
            for (int i=lane; i<nx; i+=64){
                float u = fmaf(Tr[i], -ie2, pot[i]);
                float mn = fmaxf(m,u);
                S = S*ex2(m-mn) + ex2(u-mn);
                m = mn;
            }
            #pragma unroll
            for (int o=32;o;o>>=1) lsemerge(m,S,__shfl_xor(m,o),__shfl_xor(S,o));
            lg2a += neL*(m + lg2(S) - l2nx);
        }
        if (lane==0 && lg2a!=0.f) atomicAdd(&sacc[1], lg2a);
    }
    __syncthreads();
    if (tid==0){
        if (sacc[0]!=0.f) atomicAdd(&wf[U_ACCF+p], sacc[0]);
        if (sacc[1]!=0.f) atomicAdd(&wf[U_ACCG+p], sacc[1]);
    }
    pbar(bcnt, bgen);
    if (sb==0 && tid==0){
        float af = __hip_atomic_load(&wf[U_ACCF+p], __ATOMIC_ACQUIRE, __HIP_MEMORY_SCOPE_AGENT);
        float ag = __hip_atomic_load(&wf[U_ACCG+p], __ATOMIC_ACQUIRE, __HIP_MEMORY_SCOPE_AGENT);
        float wgt = (p%3==0) ? 1.f : -0.5f;
        atomicAdd(out, wgt*(af/(float)nx + ag/(float)ny));
    }
}

extern "C" void kernel_launch(void* const* d_in, const int* in_sizes, int n_in,
                              void* d_out, int out_size, void* d_ws, size_t ws_size,
                              hipStream_t stream) {
    const float* x     = (const float*)d_in[0];
    const float* y     = (const float*)d_in[1];
    const float* cc    = (const float*)d_in[2];
    const float* ft    = (const float*)d_in[3];
    const int*   predt = (const int*)d_in[4];
    float* out = (float*)d_out;
    float* wf = (float*)d_ws;
    int*   wi = (int*)d_ws;

    hipMemsetAsync(d_ws, 0, 832*sizeof(int), stream);                     // counters/maxes/barriers
    hipMemsetAsync(wf + U_GPOT, 0, NPROB*3072*sizeof(float), stream);     // g potentials start at 0

    k_prep_x<<<12, 256, 0, stream>>>(x, cc, wf, wi);
    k_prep_y<<<12, 256, 0, stream>>>(y, predt, wf, wi);
    k_offsets<<<1, 64, 0, stream>>>(ft, wf, wi, out);   // writes out[0] = loss_fil, tables, zero accs
    k_scatter<<<24, 256, 0, stream>>>(predt, wi);
    k_maxmat<<<dim3(48,48,3), 256, 0, stream>>>(x, y, wf, wi);
    k_gather<<<1024, 256, 0, stream>>>(x, y, wf, wi);

    k_sink<<<dim3(NPROB*NBPP), 1024, 0, stream>>>(wf, wi, out);   // regular launch (graph-capturable)
}